// Round 6
// baseline (137.410 us; speedup 1.0000x reference)
//
#include <hip/hip_runtime.h>

// out[b,c,y,x] = sum_{i,j} Dot[b,3i+j,y,x] * V[b,c,y+i-1,x+j-1]  (zero-padded)
// b=16, c=64, h=w=128, fp32. Steady-state traffic ~104 MB @ 6.3 TB/s -> ~16.5 us.
// Round-5 lesson: nontemporal stores bypass L2 write-combining -> 3.4x write
// amplification (WRITE 65.5->221 MB) + RMW fetch explosion (37.7->289 MB).
// NEVER use nt for 16B-granularity stores. The 512-thread occupancy fix DID
// work (26->72%). This round: 512 threads, plain cached loads/stores.

#define HH 128
#define WW 128
#define CC 64
#define KK 9

typedef float f4 __attribute__((ext_vector_type(4)));

__device__ __forceinline__ void accum3(f4& o, float vl, const f4& vm, float vr,
                                       const f4& d0, const f4& d1, const f4& d2)
{
    o.x += d0.x * vl   + d1.x * vm.x + d2.x * vm.y;
    o.y += d0.y * vm.x + d1.y * vm.y + d2.y * vm.z;
    o.z += d0.z * vm.y + d1.z * vm.z + d2.z * vm.w;
    o.w += d0.w * vm.z + d1.w * vm.w + d2.w * vr;
}

__global__ __launch_bounds__(512, 8) void msa_conv2d_kernel(
    const float* __restrict__ Dot,
    const float* __restrict__ V,
    float* __restrict__ out)
{
    __shared__ float dotRow[2][KK][WW];   // 9216 B

    // XCD-bijective swizzle: 1024 blocks, XCD = n%8 (round-robin dispatch).
    // XCD k owns contiguous chunk [k*128, (k+1)*128) of (b,ypair) work ids.
    const int n   = blockIdx.x;
    const int L   = (n & 7) * 128 + (n >> 3);
    const int b   = L >> 6;        // 0..15
    const int yp  = L & 63;        // 0..63
    const int y0  = yp * 2;

    const int tid = threadIdx.x;

    // Stage Dot[b, 0..8, y0..y0+1, :] (each Dot row read exactly once globally).
    const float* dotBase = Dot + ((size_t)b * KK) * (HH * WW);
    for (int t = tid; t < 2 * KK * WW; t += 512) {
        const int yy  = t / (KK * WW);
        const int rem = t - yy * (KK * WW);
        const int k   = rem >> 7;
        const int x   = rem & 127;
        dotRow[yy][k][x] = dotBase[(size_t)k * (HH * WW) + (size_t)(y0 + yy) * WW + x];
    }
    __syncthreads();

    const int tx = tid & 31;     // x-quad 0..31
    const int tc = tid >> 5;     // channel sub-index 0..15
    const int x0 = tx * 4;

    // Both rows' weights for this x-quad; reused 4x per thread.
    f4 dA[KK], dB[KK];
    #pragma unroll
    for (int k = 0; k < KK; ++k) {
        dA[k] = *reinterpret_cast<const f4*>(&dotRow[0][k][x0]);
        dB[k] = *reinterpret_cast<const f4*>(&dotRow[1][k][x0]);
    }

    const bool topOK = (y0 > 0);
    const bool botOK = (y0 + 2 < HH);
    const f4 z4 = {0.f, 0.f, 0.f, 0.f};

    const float* vB = V   + ((size_t)b * CC) * (HH * WW);
    float*       oB = out + ((size_t)b * CC) * (HH * WW);

    #pragma unroll
    for (int cc = 0; cc < 4; ++cc) {
        const int c = cc * 16 + tc;
        const float* vC = vB + (size_t)c * (HH * WW) + x0;

        const f4 r0 = topOK ? *reinterpret_cast<const f4*>(vC + (size_t)(y0 - 1) * WW) : z4;
        const f4 r1 =         *reinterpret_cast<const f4*>(vC + (size_t)(y0    ) * WW);
        const f4 r2 =         *reinterpret_cast<const f4*>(vC + (size_t)(y0 + 1) * WW);
        const f4 r3 = botOK ? *reinterpret_cast<const f4*>(vC + (size_t)(y0 + 2) * WW) : z4;

        float l0 = __shfl_up(r0.w, 1, 32), h0 = __shfl_down(r0.x, 1, 32);
        float l1 = __shfl_up(r1.w, 1, 32), h1 = __shfl_down(r1.x, 1, 32);
        float l2 = __shfl_up(r2.w, 1, 32), h2 = __shfl_down(r2.x, 1, 32);
        float l3 = __shfl_up(r3.w, 1, 32), h3 = __shfl_down(r3.x, 1, 32);
        if (tx == 0)  { l0 = l1 = l2 = l3 = 0.f; }
        if (tx == 31) { h0 = h1 = h2 = h3 = 0.f; }

        f4 o0 = z4, o1 = z4;
        accum3(o0, l0, r0, h0, dA[0], dA[1], dA[2]);
        accum3(o0, l1, r1, h1, dA[3], dA[4], dA[5]);
        accum3(o0, l2, r2, h2, dA[6], dA[7], dA[8]);
        accum3(o1, l1, r1, h1, dB[0], dB[1], dB[2]);
        accum3(o1, l2, r2, h2, dB[3], dB[4], dB[5]);
        accum3(o1, l3, r3, h3, dB[6], dB[7], dB[8]);

        float* oC = oB + (size_t)c * (HH * WW) + x0;
        *reinterpret_cast<f4*>(oC + (size_t)(y0    ) * WW) = o0;
        *reinterpret_cast<f4*>(oC + (size_t)(y0 + 1) * WW) = o1;
    }
}

extern "C" void kernel_launch(void* const* d_in, const int* in_sizes, int n_in,
                              void* d_out, int out_size, void* d_ws, size_t ws_size,
                              hipStream_t stream)
{
    const float* Dot = (const float*)d_in[0];  // (16, 9, 128, 128)
    const float* V   = (const float*)d_in[1];  // (16, 64, 128, 128)
    float* out       = (float*)d_out;          // (16, 64, 128, 128)

    msa_conv2d_kernel<<<dim3(16 * 64), 512, 0, stream>>>(Dot, V, out);
}

// Round 7
// 29.242 us; speedup vs baseline: 4.6990x; 4.6990x over previous
//
#include <hip/hip_runtime.h>

// out[b,c,y,x] = sum_{i,j} Dot[b,3i+j,y,x] * V[b,c,y+i-1,x+j-1]  (zero-padded)
// b=16, c=64, h=w=128, fp32. Steady-state traffic ~104 MB @ 6.3 TB/s -> ~16.5 us.
// Round-6 lesson: __launch_bounds__(512,8) capped VGPR at 32 -> scratch spills
// -> 5x HBM traffic (FETCH 292 MB, WRITE 221 MB). NOT the nt stores.
// Fix: round-3 per-thread structure (256 thr, VGPR 64, no spill) + 2x grid
// (channel-halves) for occupancy: 2048 blocks x 4 waves = 8192 waves = 100%.

#define HH 128
#define WW 128
#define CC 64
#define KK 9

typedef float f4 __attribute__((ext_vector_type(4)));

__device__ __forceinline__ void accum3(f4& o, float vl, const f4& vm, float vr,
                                       const f4& d0, const f4& d1, const f4& d2)
{
    o.x += d0.x * vl   + d1.x * vm.x + d2.x * vm.y;
    o.y += d0.y * vm.x + d1.y * vm.y + d2.y * vm.z;
    o.z += d0.z * vm.y + d1.z * vm.z + d2.z * vm.w;
    o.w += d0.w * vm.z + d1.w * vm.w + d2.w * vr;
}

__global__ __launch_bounds__(256) void msa_conv2d_kernel(
    const float* __restrict__ Dot,
    const float* __restrict__ V,
    float* __restrict__ out)
{
    __shared__ float dotRow[2][KK][WW];   // 9216 B

    // 2048 blocks; XCD = n%8 (round-robin). XCD k owns contiguous chunk
    // [k*256, (k+1)*256) of work ids L = ((b*64 + yp)*2 + ch):
    //  - both channel-halves of a (b,yp) on same XCD  -> Dot L2 reuse
    //  - adjacent yp on same XCD                      -> V halo L2 reuse
    const int n   = blockIdx.x;
    const int L   = (n & 7) * 256 + (n >> 3);
    const int b   = L >> 7;             // 0..15
    const int rem = L & 127;
    const int yp  = rem >> 1;           // 0..63
    const int ch  = rem & 1;            // channel half, 0..1
    const int y0  = yp * 2;

    const int tid = threadIdx.x;

    // Stage Dot[b, 0..8, y0..y0+1, :].
    const float* dotBase = Dot + ((size_t)b * KK) * (HH * WW);
    for (int t = tid; t < 2 * KK * WW; t += 256) {
        const int yy  = t / (KK * WW);
        const int r   = t - yy * (KK * WW);
        const int k   = r >> 7;
        const int x   = r & 127;
        dotRow[yy][k][x] = dotBase[(size_t)k * (HH * WW) + (size_t)(y0 + yy) * WW + x];
    }
    __syncthreads();

    const int tx = tid & 31;     // x-quad 0..31
    const int tc = tid >> 5;     // channel sub-index 0..7
    const int x0 = tx * 4;

    // Both rows' weights for this x-quad; compiler keeps/re-reads from LDS
    // as register budget allows (VGPR=64 proven spill-free in round 3).
    f4 dA[KK], dB[KK];
    #pragma unroll
    for (int k = 0; k < KK; ++k) {
        dA[k] = *reinterpret_cast<const f4*>(&dotRow[0][k][x0]);
        dB[k] = *reinterpret_cast<const f4*>(&dotRow[1][k][x0]);
    }

    const bool topOK = (y0 > 0);
    const bool botOK = (y0 + 2 < HH);
    const f4 z4 = {0.f, 0.f, 0.f, 0.f};

    const float* vB = V   + ((size_t)b * CC) * (HH * WW);
    float*       oB = out + ((size_t)b * CC) * (HH * WW);

    #pragma unroll
    for (int cc = 0; cc < 4; ++cc) {
        const int c = ch * 32 + cc * 8 + tc;
        const float* vC = vB + (size_t)c * (HH * WW) + x0;

        const f4 r0 = topOK ? *reinterpret_cast<const f4*>(vC + (size_t)(y0 - 1) * WW) : z4;
        const f4 r1 =         *reinterpret_cast<const f4*>(vC + (size_t)(y0    ) * WW);
        const f4 r2 =         *reinterpret_cast<const f4*>(vC + (size_t)(y0 + 1) * WW);
        const f4 r3 = botOK ? *reinterpret_cast<const f4*>(vC + (size_t)(y0 + 2) * WW) : z4;

        float l0 = __shfl_up(r0.w, 1, 32), h0 = __shfl_down(r0.x, 1, 32);
        float l1 = __shfl_up(r1.w, 1, 32), h1 = __shfl_down(r1.x, 1, 32);
        float l2 = __shfl_up(r2.w, 1, 32), h2 = __shfl_down(r2.x, 1, 32);
        float l3 = __shfl_up(r3.w, 1, 32), h3 = __shfl_down(r3.x, 1, 32);
        if (tx == 0)  { l0 = l1 = l2 = l3 = 0.f; }
        if (tx == 31) { h0 = h1 = h2 = h3 = 0.f; }

        f4 o0 = z4, o1 = z4;
        accum3(o0, l0, r0, h0, dA[0], dA[1], dA[2]);
        accum3(o0, l1, r1, h1, dA[3], dA[4], dA[5]);
        accum3(o0, l2, r2, h2, dA[6], dA[7], dA[8]);
        accum3(o1, l1, r1, h1, dB[0], dB[1], dB[2]);
        accum3(o1, l2, r2, h2, dB[3], dB[4], dB[5]);
        accum3(o1, l3, r3, h3, dB[6], dB[7], dB[8]);

        float* oC = oB + (size_t)c * (HH * WW) + x0;
        *reinterpret_cast<f4*>(oC + (size_t)(y0    ) * WW) = o0;
        *reinterpret_cast<f4*>(oC + (size_t)(y0 + 1) * WW) = o1;
    }
}

extern "C" void kernel_launch(void* const* d_in, const int* in_sizes, int n_in,
                              void* d_out, int out_size, void* d_ws, size_t ws_size,
                              hipStream_t stream)
{
    const float* Dot = (const float*)d_in[0];  // (16, 9, 128, 128)
    const float* V   = (const float*)d_in[1];  // (16, 64, 128, 128)
    float* out       = (float*)d_out;          // (16, 64, 128, 128)

    msa_conv2d_kernel<<<dim3(2048), 256, 0, stream>>>(Dot, V, out);
}

// Round 8
// 27.814 us; speedup vs baseline: 4.9402x; 1.0513x over previous
//
#include <hip/hip_runtime.h>

// out[b,c,y,x] = sum_{i,j} Dot[b,3i+j,y,x] * V[b,c,y+i-1,x+j-1]  (zero-padded)
// b=16, c=64, h=w=128, fp32. HBM steady-state ~103 MB (inputs partly L3-hot).
// Round-7 lesson: grid-doubling changed nothing (26% occ, 15% VALU, 3.6 TB/s)
// -> waves stall serially on 4 load round-trips (VGPR=60 forced cc-serial).
// Fix: explicit load/compute phase split -> all 16 V loads in flight before
// any use; vectorized Dot staging; let VGPR grow (no min-waves bound).

#define HH 128
#define WW 128
#define CC 64
#define KK 9

typedef float f4 __attribute__((ext_vector_type(4)));

__device__ __forceinline__ void accum3(f4& o, float vl, const f4& vm, float vr,
                                       const f4& d0, const f4& d1, const f4& d2)
{
    o.x += d0.x * vl   + d1.x * vm.x + d2.x * vm.y;
    o.y += d0.y * vm.x + d1.y * vm.y + d2.y * vm.z;
    o.z += d0.z * vm.y + d1.z * vm.z + d2.z * vm.w;
    o.w += d0.w * vm.z + d1.w * vm.w + d2.w * vr;
}

__global__ __launch_bounds__(256) void msa_conv2d_kernel(
    const float* __restrict__ Dot,
    const float* __restrict__ V,
    float* __restrict__ out)
{
    __shared__ float dotRow[2][KK][WW];   // 9216 B

    // 2048 blocks; XCD = n%8 (round-robin). XCD k owns contiguous chunk
    // [k*256, (k+1)*256) of work ids L = ((b*64 + yp)*2 + ch).
    const int n   = blockIdx.x;
    const int L   = (n & 7) * 256 + (n >> 3);
    const int b   = L >> 7;             // 0..15
    const int rem = L & 127;
    const int yp  = rem >> 1;           // 0..63
    const int ch  = rem & 1;            // channel half, 0..1
    const int y0  = yp * 2;

    const int tid = threadIdx.x;

    // Stage Dot[b, 0..8, y0..y0+1, :] with float4 loads (576 f4 / block).
    const float* dotBase = Dot + ((size_t)b * KK) * (HH * WW);
    f4* dotLds = reinterpret_cast<f4*>(&dotRow[0][0][0]);
    for (int t = tid; t < 2 * KK * 32; t += 256) {
        const int yy = t / (KK * 32);
        const int r  = t - yy * (KK * 32);
        const int k  = r >> 5;
        const int x4 = r & 31;
        dotLds[t] = *reinterpret_cast<const f4*>(
            dotBase + (size_t)k * (HH * WW) + (size_t)(y0 + yy) * WW + x4 * 4);
    }
    __syncthreads();

    const int tx = tid & 31;     // x-quad 0..31
    const int tc = tid >> 5;     // channel sub-index 0..7
    const int x0 = tx * 4;

    const bool topOK = (y0 > 0);
    const bool botOK = (y0 + 2 < HH);
    const f4 z4 = {0.f, 0.f, 0.f, 0.f};

    const float* vB = V   + ((size_t)b * CC) * (HH * WW);
    float*       oB = out + ((size_t)b * CC) * (HH * WW);

    // ---- Load phase: all 16 V float4s in flight (static indexing only). ----
    f4 r[4][4];
    #pragma unroll
    for (int cc = 0; cc < 4; ++cc) {
        const int c = ch * 32 + cc * 8 + tc;
        const float* vC = vB + (size_t)c * (HH * WW) + x0;
        r[cc][0] = topOK ? *reinterpret_cast<const f4*>(vC + (size_t)(y0 - 1) * WW) : z4;
        r[cc][1] =         *reinterpret_cast<const f4*>(vC + (size_t)(y0    ) * WW);
        r[cc][2] =         *reinterpret_cast<const f4*>(vC + (size_t)(y0 + 1) * WW);
        r[cc][3] = botOK ? *reinterpret_cast<const f4*>(vC + (size_t)(y0 + 2) * WW) : z4;
    }

    // Weights hoisted once (18 ds_read_b128/thread, shared across all 4 cc).
    f4 dA[KK], dB[KK];
    #pragma unroll
    for (int k = 0; k < KK; ++k) {
        dA[k] = *reinterpret_cast<const f4*>(&dotRow[0][k][x0]);
        dB[k] = *reinterpret_cast<const f4*>(&dotRow[1][k][x0]);
    }

    // ---- Compute + store phase. ----
    #pragma unroll
    for (int cc = 0; cc < 4; ++cc) {
        const int c = ch * 32 + cc * 8 + tc;

        float l0 = __shfl_up(r[cc][0].w, 1, 32), h0 = __shfl_down(r[cc][0].x, 1, 32);
        float l1 = __shfl_up(r[cc][1].w, 1, 32), h1 = __shfl_down(r[cc][1].x, 1, 32);
        float l2 = __shfl_up(r[cc][2].w, 1, 32), h2 = __shfl_down(r[cc][2].x, 1, 32);
        float l3 = __shfl_up(r[cc][3].w, 1, 32), h3 = __shfl_down(r[cc][3].x, 1, 32);
        if (tx == 0)  { l0 = l1 = l2 = l3 = 0.f; }
        if (tx == 31) { h0 = h1 = h2 = h3 = 0.f; }

        f4 o0 = z4, o1 = z4;
        accum3(o0, l0, r[cc][0], h0, dA[0], dA[1], dA[2]);
        accum3(o0, l1, r[cc][1], h1, dA[3], dA[4], dA[5]);
        accum3(o0, l2, r[cc][2], h2, dA[6], dA[7], dA[8]);
        accum3(o1, l1, r[cc][1], h1, dB[0], dB[1], dB[2]);
        accum3(o1, l2, r[cc][2], h2, dB[3], dB[4], dB[5]);
        accum3(o1, l3, r[cc][3], h3, dB[6], dB[7], dB[8]);

        float* oC = oB + (size_t)c * (HH * WW) + x0;
        *reinterpret_cast<f4*>(oC + (size_t)(y0    ) * WW) = o0;
        *reinterpret_cast<f4*>(oC + (size_t)(y0 + 1) * WW) = o1;
    }
}

extern "C" void kernel_launch(void* const* d_in, const int* in_sizes, int n_in,
                              void* d_out, int out_size, void* d_ws, size_t ws_size,
                              hipStream_t stream)
{
    const float* Dot = (const float*)d_in[0];  // (16, 9, 128, 128)
    const float* V   = (const float*)d_in[1];  // (16, 64, 128, 128)
    float* out       = (float*)d_out;          // (16, 64, 128, 128)

    msa_conv2d_kernel<<<dim3(2048), 256, 0, stream>>>(Dot, V, out);
}